// Round 1
// baseline (3989.780 us; speedup 1.0000x reference)
//
#include <hip/hip_runtime.h>
#include <cmath>

// Problem constants
#define BB 4
#define LL 2048
#define DD 1024
#define HH 8
#define EE 128
#define MM (BB * LL)   // 8192 rows

struct Gammas { float lg2[8]; };

// ---------------------------------------------------------------------------
// xpos table: tbl[l*64 + i] = {cos*scale, sin*scale, cos/scale, sin/scale}
// ---------------------------------------------------------------------------
__global__ void xpos_table_kernel(float4* __restrict__ tbl) {
    int tid = blockIdx.x * blockDim.x + threadIdx.x;  // 2048*64
    if (tid >= LL * 64) return;
    int l = tid >> 6, i = tid & 63;
    float inv = powf(10000.0f, -(float)i / 64.0f);
    float ang = (float)l * inv;
    float s = sinf(ang), c = cosf(ang);
    float base = (2.0f * (float)i + 51.2f) / 179.2f;   // (2i + 0.4*128)/(1.4*128)
    float sc = powf(base, (float)l / 512.0f);
    tbl[tid] = make_float4(c * sc, s * sc, c / sc, s / sc);
}

// ---------------------------------------------------------------------------
// fp32 GEMM: C[8192 x 1024] = A[8192 x 1024(K)] * W
// wmode: perhead=1 -> W laid out (h, d, e) [QKV weights], ldw=128
//        perhead=0 -> W laid out (d, n), ldw=1024
// emode: 0 none, 1 xpos up (Q), 2 xpos down (K), 3 silu (G)
// ---------------------------------------------------------------------------
__global__ __launch_bounds__(256) void gemm_kernel(
    const float* __restrict__ A, const float* __restrict__ W, float* C,
    int ldw, int perhead, int emode, const float4* __restrict__ tbl)
{
    __shared__ float As[16][132];   // A^T tile: As[k][m]
    __shared__ float Bs[16][132];   // Bs[k][n]
    const int t = threadIdx.x;
    const int n0 = blockIdx.x * 128;
    const int m0 = blockIdx.y * 128;
    const int u = t & 15, v = t >> 4;

    float acc[8][8] = {};

    const size_t wbase = perhead ? (size_t)blockIdx.x * 131072 : (size_t)n0;
    const int arow = t >> 2, akq = (t & 3) * 4;

    for (int kt = 0; kt < 1024; kt += 16) {
        float4 a0 = *(const float4*)&A[(size_t)(m0 + arow) * 1024 + kt + akq];
        float4 a1 = *(const float4*)&A[(size_t)(m0 + arow + 64) * 1024 + kt + akq];
        float4 b0 = *(const float4*)&W[wbase + (size_t)(kt + v) * ldw + u * 4];
        float4 b1 = *(const float4*)&W[wbase + (size_t)(kt + v) * ldw + 64 + u * 4];
        __syncthreads();
        As[akq + 0][arow] = a0.x; As[akq + 1][arow] = a0.y;
        As[akq + 2][arow] = a0.z; As[akq + 3][arow] = a0.w;
        As[akq + 0][arow + 64] = a1.x; As[akq + 1][arow + 64] = a1.y;
        As[akq + 2][arow + 64] = a1.z; As[akq + 3][arow + 64] = a1.w;
        *(float4*)&Bs[v][u * 4] = b0;
        *(float4*)&Bs[v][64 + u * 4] = b1;
        __syncthreads();
        #pragma unroll
        for (int k = 0; k < 16; k++) {
            float4 la0 = *(float4*)&As[k][u * 4];
            float4 la1 = *(float4*)&As[k][64 + u * 4];
            float4 lb0 = *(float4*)&Bs[k][v * 4];
            float4 lb1 = *(float4*)&Bs[k][64 + v * 4];
            float ar[8] = {la0.x, la0.y, la0.z, la0.w, la1.x, la1.y, la1.z, la1.w};
            float br[8] = {lb0.x, lb0.y, lb0.z, lb0.w, lb1.x, lb1.y, lb1.z, lb1.w};
            #pragma unroll
            for (int i = 0; i < 8; i++)
                #pragma unroll
                for (int j = 0; j < 8; j++)
                    acc[i][j] = fmaf(ar[i], br[j], acc[i][j]);
        }
    }

    // epilogue
    if (emode == 1 || emode == 2) {
        #pragma unroll
        for (int i = 0; i < 8; i++) {
            int r = m0 + u * 4 + (i & 3) + ((i >> 2) << 6);
            int l = r & (LL - 1);
            #pragma unroll
            for (int p = 0; p < 4; p++) {
                int ip = (p & 1) + 2 * v + ((p >> 1) * 32);
                float4 tt = tbl[l * 64 + ip];
                float cc = (emode == 1) ? tt.x : tt.z;
                float ss = (emode == 1) ? tt.y : tt.w;
                float x0 = acc[i][2 * p], x1 = acc[i][2 * p + 1];
                acc[i][2 * p]     = x0 * cc - x1 * ss;
                acc[i][2 * p + 1] = x1 * cc + x0 * ss;
            }
        }
    } else if (emode == 3) {
        #pragma unroll
        for (int i = 0; i < 8; i++)
            #pragma unroll
            for (int j = 0; j < 8; j++) {
                float g = acc[i][j];
                acc[i][j] = g / (1.0f + expf(-g));
            }
    }

    #pragma unroll
    for (int i = 0; i < 8; i++) {
        int r = m0 + u * 4 + (i & 3) + ((i >> 2) << 6);
        float4 s0 = make_float4(acc[i][0], acc[i][1], acc[i][2], acc[i][3]);
        float4 s1 = make_float4(acc[i][4], acc[i][5], acc[i][6], acc[i][7]);
        *(float4*)&C[(size_t)r * 1024 + n0 + v * 4] = s0;
        *(float4*)&C[(size_t)r * 1024 + n0 + 64 + v * 4] = s1;
    }
}

// ---------------------------------------------------------------------------
// Retention: per (b,h, 64-row block). Causal decay-weighted attention (no
// softmax). Q rows in LDS, K in 32-row LDS chunks, scores->LDS, V streamed
// from global (L2-resident). Y written over the Q region (disjoint per block).
// ---------------------------------------------------------------------------
__global__ __launch_bounds__(256) void retention_kernel(
    const float* __restrict__ Q, const float* __restrict__ K,
    const float* __restrict__ V, float* Y, Gammas gp)
{
    __shared__ float Qs[64][132];
    __shared__ float Ks[32][132];
    __shared__ float Ss[64][36];

    const int t = threadIdx.x;
    const int n0 = blockIdx.x * 64;          // query-row block
    const int bh = blockIdx.y;               // b*8 + h
    const int b = bh >> 3, h = bh & 7;
    const float lg2 = gp.lg2[h];
    const size_t rowbase = (size_t)b * LL * 1024 + (size_t)h * 128;

    // load 64 Q rows
    for (int f = t; f < 64 * 32; f += 256) {
        int row = f >> 5, c4 = (f & 31) * 4;
        *(float4*)&Qs[row][c4] =
            *(const float4*)&Q[rowbase + (size_t)(n0 + row) * 1024 + c4];
    }

    float4 acc[8];
    #pragma unroll
    for (int j = 0; j < 8; j++) acc[j] = make_float4(0.f, 0.f, 0.f, 0.f);

    const int u = t & 15, w = t >> 4;            // score phase: 4n x 2m
    const int n8 = (t >> 5) * 8, v4 = (t & 31) * 4;  // Y phase: 8n x 4v
    const int nchunks = n0 / 32 + 2;

    __syncthreads();
    for (int c = 0; c < nchunks; c++) {
        const int m0 = c * 32;
        // load K chunk
        for (int f = t; f < 32 * 32; f += 256) {
            int row = f >> 5, c4 = (f & 31) * 4;
            *(float4*)&Ks[row][c4] =
                *(const float4*)&K[rowbase + (size_t)(m0 + row) * 1024 + c4];
        }
        __syncthreads();
        // scores
        float dots[4][2] = {};
        #pragma unroll 8
        for (int e = 0; e < 128; e += 4) {
            float4 k0 = *(float4*)&Ks[2 * w][e];
            float4 k1 = *(float4*)&Ks[2 * w + 1][e];
            #pragma unroll
            for (int i = 0; i < 4; i++) {
                float4 q = *(float4*)&Qs[u + 16 * i][e];
                dots[i][0] += q.x * k0.x + q.y * k0.y + q.z * k0.z + q.w * k0.w;
                dots[i][1] += q.x * k1.x + q.y * k1.y + q.z * k1.z + q.w * k1.w;
            }
        }
        #pragma unroll
        for (int i = 0; i < 4; i++)
            #pragma unroll
            for (int j = 0; j < 2; j++) {
                int n = n0 + u + 16 * i, m = m0 + 2 * w + j;
                float val = 0.0f;
                if (m <= n) val = dots[i][j] * exp2f((float)(n - m) * lg2);
                Ss[u + 16 * i][2 * w + j] = val;
            }
        __syncthreads();
        // Y accumulate: V from global (L2)
        #pragma unroll
        for (int m4 = 0; m4 < 32; m4 += 4) {
            float4 vv[4];
            #pragma unroll
            for (int q2 = 0; q2 < 4; q2++)
                vv[q2] = *(const float4*)&V[rowbase + (size_t)(m0 + m4 + q2) * 1024 + v4];
            #pragma unroll
            for (int j = 0; j < 8; j++) {
                float4 sj = *(float4*)&Ss[n8 + j][m4];
                acc[j].x += sj.x * vv[0].x + sj.y * vv[1].x + sj.z * vv[2].x + sj.w * vv[3].x;
                acc[j].y += sj.x * vv[0].y + sj.y * vv[1].y + sj.z * vv[2].y + sj.w * vv[3].y;
                acc[j].z += sj.x * vv[0].z + sj.y * vv[1].z + sj.z * vv[2].z + sj.w * vv[3].z;
                acc[j].w += sj.x * vv[0].w + sj.y * vv[1].w + sj.z * vv[2].w + sj.w * vv[3].w;
            }
        }
        __syncthreads();
    }
    // write Y (over Q region; only this block touches these addresses)
    #pragma unroll
    for (int j = 0; j < 8; j++)
        *(float4*)&Y[rowbase + (size_t)(n0 + n8 + j) * 1024 + v4] = acc[j];
}

// ---------------------------------------------------------------------------
// GroupNorm over each (b,l,h) 128-vector + affine + gate with silu(G).
// In-place on Y (one wave per group).
// ---------------------------------------------------------------------------
__global__ __launch_bounds__(256) void gn_gate_kernel(
    float* Y, const float* __restrict__ G,
    const float* __restrict__ gnw, const float* __restrict__ gnb)
{
    const int t = threadIdx.x;
    const int g = blockIdx.x * 4 + (t >> 6);   // group = ((b*L+l)*8 + h)
    const int lane = t & 63;
    const size_t r = (size_t)(g >> 3);
    const int h = g & 7;
    const int e = h * 128 + lane * 2;
    const size_t base = r * 1024 + e;
    float2 y = *(float2*)&Y[base];
    float s = y.x + y.y;
    float sq = y.x * y.x + y.y * y.y;
    #pragma unroll
    for (int off = 32; off >= 1; off >>= 1) {
        s  += __shfl_xor(s, off, 64);
        sq += __shfl_xor(sq, off, 64);
    }
    float mean = s * 0.0078125f;
    float var = sq * 0.0078125f - mean * mean;
    float rstd = rsqrtf(var + 1e-5f);
    float2 gw = *(const float2*)&gnw[e];
    float2 gb = *(const float2*)&gnb[e];
    float2 gg = *(const float2*)&G[base];
    float2 out;
    out.x = ((y.x - mean) * rstd * gw.x + gb.x) * gg.x;
    out.y = ((y.y - mean) * rstd * gw.y + gb.y) * gg.y;
    *(float2*)&Y[base] = out;
}

// ---------------------------------------------------------------------------
extern "C" void kernel_launch(void* const* d_in, const int* in_sizes, int n_in,
                              void* d_out, int out_size, void* d_ws, size_t ws_size,
                              hipStream_t stream) {
    const float* X   = (const float*)d_in[0];
    const float* Wq  = (const float*)d_in[1];
    const float* Wk  = (const float*)d_in[2];
    const float* Wv  = (const float*)d_in[3];
    const float* Wg  = (const float*)d_in[4];
    const float* Wo  = (const float*)d_in[5];
    const float* gnw = (const float*)d_in[6];
    const float* gnb = (const float*)d_in[7];
    float* out = (float*)d_out;

    // workspace layout (floats): Q(=Y=A) | K | V | G | xpos table
    float* Qp = (float*)d_ws;
    float* Kp = Qp + (size_t)MM * 1024;
    float* Vp = Kp + (size_t)MM * 1024;
    float* Gp = Vp + (size_t)MM * 1024;
    float4* tbl = (float4*)(Gp + (size_t)MM * 1024);

    Gammas gp;
    for (int h = 0; h < 8; h++) {
        double lin = log(1.0 / 32.0) +
                     (log(1.0 / 512.0) - log(1.0 / 32.0)) * (double)h / 7.0;
        float gamma = 1.0f - expf((float)lin);
        gp.lg2[h] = log2f(gamma);
    }

    xpos_table_kernel<<<(LL * 64) / 256, 256, 0, stream>>>(tbl);

    dim3 ggrid(8, 64);
    gemm_kernel<<<ggrid, 256, 0, stream>>>(X, Wq, Qp, 128, 1, 1, tbl);
    gemm_kernel<<<ggrid, 256, 0, stream>>>(X, Wk, Kp, 128, 1, 2, tbl);
    gemm_kernel<<<ggrid, 256, 0, stream>>>(X, Wv, Vp, 128, 1, 0, tbl);
    gemm_kernel<<<ggrid, 256, 0, stream>>>(X, Wg, Gp, 1024, 0, 3, tbl);

    retention_kernel<<<dim3(LL / 64, BB * HH), 256, 0, stream>>>(Qp, Kp, Vp, Qp, gp);

    gn_gate_kernel<<<(MM * HH) / 4, 256, 0, stream>>>(Qp, Gp, gnw, gnb);

    gemm_kernel<<<ggrid, 256, 0, stream>>>(Qp, Wo, out, 1024, 0, 0, tbl);
}

// Round 2
// 603.282 us; speedup vs baseline: 6.6135x; 6.6135x over previous
//
#include <hip/hip_runtime.h>
#include <cmath>

#define BB 4
#define LL 2048
#define DD 1024
#define HH 8
#define MM (BB * LL)   // 8192 rows

struct Gammas { float lg2[8]; };

typedef __attribute__((ext_vector_type(8))) short bf16x8;
typedef __attribute__((ext_vector_type(4))) float f32x4;

__device__ __forceinline__ ushort f2bf(float f) {
    uint u = __builtin_bit_cast(uint, f);
    uint r = (u + 0x7fffu + ((u >> 16) & 1u)) >> 16;
    return (ushort)r;
}
__device__ __forceinline__ float bf2f(ushort h) {
    uint u = ((uint)h) << 16;
    return __builtin_bit_cast(float, u);
}
__device__ __forceinline__ void gload16(const void* g, void* l) {
    __builtin_amdgcn_global_load_lds((const __attribute__((address_space(1))) void*)g,
                                     (__attribute__((address_space(3))) void*)l, 16, 0, 0);
}

// ---------------------------------------------------------------------------
// xpos table: tbl[l*64 + i] = {cos*scale, sin*scale, cos/scale, sin/scale}
// ---------------------------------------------------------------------------
__global__ void xpos_table_kernel(float4* __restrict__ tbl) {
    int tid = blockIdx.x * blockDim.x + threadIdx.x;
    if (tid >= LL * 64) return;
    int l = tid >> 6, i = tid & 63;
    float inv = powf(10000.0f, -(float)i / 64.0f);
    float ang = (float)l * inv;
    float s = sinf(ang), c = cosf(ang);
    float base = (2.0f * (float)i + 51.2f) / 179.2f;
    float sc = powf(base, (float)l / 512.0f);
    tbl[tid] = make_float4(c * sc, s * sc, c / sc, s / sc);
}

// fp32 -> bf16 elementwise cast (X)
__global__ __launch_bounds__(256) void cast_kernel(const float* __restrict__ X,
                                                   ushort* __restrict__ Xb) {
    int i = (blockIdx.x * 256 + threadIdx.x) * 4;
    float4 v = *(const float4*)&X[i];
    ushort4 o;
    o.x = f2bf(v.x); o.y = f2bf(v.y); o.z = f2bf(v.z); o.w = f2bf(v.w);
    *(ushort4*)&Xb[i] = o;
}

// ---------------------------------------------------------------------------
// Weight transpose+cast: W[k][n] (flat or per-head (h,d,e)) -> Wt[n][k] bf16
// ---------------------------------------------------------------------------
__global__ __launch_bounds__(256) void wtrans_kernel(const float* __restrict__ W,
                                                     ushort* __restrict__ Wt, int perhead) {
    __shared__ float T[64][68];
    const int k0 = blockIdx.y * 64, n0 = blockIdx.x * 64;
    const int t = threadIdx.x;
    for (int f = t; f < 64 * 16; f += 256) {
        int kk = f >> 4, s = f & 15;
        int n = n0 + s * 4;
        size_t src = perhead ? (size_t)(n >> 7) * 131072 + (size_t)(k0 + kk) * 128 + (n & 127)
                             : (size_t)(k0 + kk) * 1024 + n;
        *(float4*)&T[kk][s * 4] = *(const float4*)&W[src];
    }
    __syncthreads();
    for (int f = t; f < 64 * 8; f += 256) {
        int n = f >> 3, s = f & 7;
        __align__(16) ushort tmp[8];
        #pragma unroll
        for (int j = 0; j < 8; j++) tmp[j] = f2bf(T[s * 8 + j][n]);
        *(uint4*)&Wt[(size_t)(n0 + n) * 1024 + k0 + s * 8] = *(uint4*)tmp;
    }
}

// ---------------------------------------------------------------------------
// bf16 MFMA GEMM: C[8192 x 1024] = A[8192 x 1024] * Bt^T   (Bt is [n][k])
// emode: 0 plain->bf16, 1 xpos up->bf16, 2 xpos down->bf16, 3 silu->bf16,
//        4 plain->fp32
// ---------------------------------------------------------------------------
__global__ __launch_bounds__(256) void mm_kernel(
    const ushort* __restrict__ A, const ushort* __restrict__ Bt,
    void* __restrict__ Cv, int emode, const float4* __restrict__ tbl)
{
    __shared__ __align__(16) ushort As[128 * 32];
    __shared__ __align__(16) ushort Bs[128 * 32];
    const int t = threadIdx.x;
    const int w = t >> 6, lane = t & 63;
    const int ln = lane & 15, quad = lane >> 4;
    const int n0 = blockIdx.x * 128, m0 = blockIdx.y * 128;
    const int wm = w & 1, wn = w >> 1;

    f32x4 acc[4][4];
    const f32x4 fzero = {0.f, 0.f, 0.f, 0.f};
    #pragma unroll
    for (int i = 0; i < 4; i++)
        #pragma unroll
        for (int j = 0; j < 4; j++) acc[i][j] = fzero;

    const int srow = w * 32 + (lane >> 2);
    const int scol = (lane & 3) * 8;
    const ushort* ga  = A  + (size_t)(m0 + srow) * 1024 + scol;
    const ushort* ga2 = ga + 16 * 1024;
    const ushort* gb  = Bt + (size_t)(n0 + srow) * 1024 + scol;
    const ushort* gb2 = gb + 16 * 1024;
    ushort* la  = &As[(w * 32) * 32];
    ushort* la2 = &As[(w * 32 + 16) * 32];
    ushort* lb  = &Bs[(w * 32) * 32];
    ushort* lb2 = &Bs[(w * 32 + 16) * 32];

    for (int kt = 0; kt < 1024; kt += 32) {
        gload16(ga + kt, la);
        gload16(ga2 + kt, la2);
        gload16(gb + kt, lb);
        gload16(gb2 + kt, lb2);
        __syncthreads();
        bf16x8 am[4], bn[4];
        #pragma unroll
        for (int i = 0; i < 4; i++)
            am[i] = *(const bf16x8*)&As[(wm * 64 + i * 16 + ln) * 32 + quad * 8];
        #pragma unroll
        for (int i = 0; i < 4; i++)
            bn[i] = *(const bf16x8*)&Bs[(wn * 64 + i * 16 + ln) * 32 + quad * 8];
        #pragma unroll
        for (int mi = 0; mi < 4; mi++)
            #pragma unroll
            for (int ni = 0; ni < 4; ni++)
                acc[mi][ni] = __builtin_amdgcn_mfma_f32_16x16x32_bf16(
                    am[mi], bn[ni], acc[mi][ni], 0, 0, 0);
        __syncthreads();
    }

    // epilogue
    #pragma unroll
    for (int mi = 0; mi < 4; mi++) {
        #pragma unroll
        for (int ni = 0; ni < 4; ni++) {
            const int row0 = m0 + wm * 64 + mi * 16 + quad * 4;
            const int e = wn * 64 + ni * 16 + ln;       // col within head
            const int col = n0 + e;
            #pragma unroll
            for (int r = 0; r < 4; r++) {
                float v = acc[mi][ni][r];
                if (emode == 1 || emode == 2) {
                    float4 tt = tbl[(size_t)((row0 + r) & (LL - 1)) * 64 + (e >> 1)];
                    float cc = (emode == 1) ? tt.x : tt.z;
                    float ss = (emode == 1) ? tt.y : tt.w;
                    float partner = __shfl_xor(v, 1);
                    float rot = (e & 1) ? partner : -partner;
                    v = v * cc + rot * ss;
                } else if (emode == 3) {
                    v = v / (1.0f + expf(-v));
                }
                if (emode == 4)
                    ((float*)Cv)[(size_t)(row0 + r) * 1024 + col] = v;
                else
                    ((ushort*)Cv)[(size_t)(row0 + r) * 1024 + col] = f2bf(v);
            }
        }
    }
}

// ---------------------------------------------------------------------------
// V transpose: V[8192 m][1024 n] bf16 -> Vt[b][n][l] bf16   (l stride 1)
// ---------------------------------------------------------------------------
__global__ __launch_bounds__(256) void vtrans_kernel(const ushort* __restrict__ V,
                                                     ushort* __restrict__ Vt) {
    __shared__ ushort T[64][72];
    const int m0 = blockIdx.y * 64, n0 = blockIdx.x * 64;
    const int t = threadIdx.x;
    for (int f = t; f < 64 * 8; f += 256) {
        int r = f >> 3, s = f & 7;
        *(uint4*)&T[r][s * 8] = *(const uint4*)&V[(size_t)(m0 + r) * 1024 + n0 + s * 8];
    }
    __syncthreads();
    const int b = m0 >> 11, l0 = m0 & (LL - 1);
    for (int f = t; f < 64 * 8; f += 256) {
        int n = f >> 3, s = f & 7;
        __align__(16) ushort tmp[8];
        #pragma unroll
        for (int j = 0; j < 8; j++) tmp[j] = T[s * 8 + j][n];
        *(uint4*)&Vt[((size_t)(b * 1024 + n0 + n)) * 2048 + l0 + s * 8] = *(uint4*)tmp;
    }
}

// ---------------------------------------------------------------------------
// Retention (MFMA): per (b,h, 64-query block). S=QK^T*decay, Y=S*V.
// ---------------------------------------------------------------------------
__global__ __launch_bounds__(256) void ret_kernel(
    const ushort* __restrict__ Qb, const ushort* __restrict__ Kb,
    const ushort* __restrict__ Vt, float* __restrict__ Y, Gammas gp)
{
    __shared__ __align__(16) ushort Qs[64][136];
    __shared__ __align__(16) ushort Ks[64][136];
    __shared__ __align__(16) ushort Vs[128][72];
    __shared__ __align__(16) ushort Ss[64][72];

    const int t = threadIdx.x;
    const int w = t >> 6, lane = t & 63, ln = lane & 15, quad = lane >> 4;
    const int qb = 31 - blockIdx.x;            // heavy blocks first
    const int n0 = qb * 64;
    const int bh = blockIdx.y, b = bh >> 3, h = bh & 7;
    const float lg2 = gp.lg2[h];
    const size_t qkbase = (size_t)b * LL * 1024 + (size_t)h * 128;
    const size_t vtbase = ((size_t)b * 1024 + h * 128) * 2048;

    for (int f = t; f < 64 * 16; f += 256) {
        int r = f >> 4, s = f & 15;
        *(uint4*)&Qs[r][s * 8] = *(const uint4*)&Qb[qkbase + (size_t)(n0 + r) * 1024 + s * 8];
    }

    const f32x4 fzero = {0.f, 0.f, 0.f, 0.f};
    f32x4 y[8];
    #pragma unroll
    for (int vt = 0; vt < 8; vt++) y[vt] = fzero;

    float dmv[4];
    #pragma unroll
    for (int kt = 0; kt < 4; kt++)
        dmv[kt] = exp2f(-(float)(kt * 16 + ln) * lg2);

    for (int c = 0; c <= qb; c++) {
        const int m0 = c * 64;
        for (int f = t; f < 64 * 16; f += 256) {
            int r = f >> 4, s = f & 15;
            *(uint4*)&Ks[r][s * 8] = *(const uint4*)&Kb[qkbase + (size_t)(m0 + r) * 1024 + s * 8];
        }
        for (int f = t; f < 128 * 8; f += 256) {
            int r = f >> 3, s = f & 7;
            *(uint4*)&Vs[r][s * 8] = *(const uint4*)&Vt[vtbase + (size_t)r * 2048 + m0 + s * 8];
        }
        __syncthreads();

        f32x4 s4[4];
        #pragma unroll
        for (int kt = 0; kt < 4; kt++) s4[kt] = fzero;
        #pragma unroll
        for (int ks = 0; ks < 4; ks++) {
            bf16x8 aq = *(const bf16x8*)&Qs[16 * w + ln][ks * 32 + quad * 8];
            #pragma unroll
            for (int kt = 0; kt < 4; kt++) {
                bf16x8 bk = *(const bf16x8*)&Ks[kt * 16 + ln][ks * 32 + quad * 8];
                s4[kt] = __builtin_amdgcn_mfma_f32_16x16x32_bf16(aq, bk, s4[kt], 0, 0, 0);
            }
        }

        const int nrel = 16 * w + quad * 4;    // query row rel. to block
        float dn[4];
        #pragma unroll
        for (int r = 0; r < 4; r++)
            dn[r] = exp2f((float)(n0 - m0 + nrel + r) * lg2);

        if (c == qb) {
            #pragma unroll
            for (int kt = 0; kt < 4; kt++)
                #pragma unroll
                for (int r = 0; r < 4; r++) {
                    float val = (kt * 16 + ln <= nrel + r)
                              ? s4[kt][r] * dn[r] * dmv[kt] : 0.0f;
                    Ss[nrel + r][kt * 16 + ln] = f2bf(val);
                }
        } else {
            #pragma unroll
            for (int kt = 0; kt < 4; kt++)
                #pragma unroll
                for (int r = 0; r < 4; r++)
                    Ss[nrel + r][kt * 16 + ln] = f2bf(s4[kt][r] * dn[r] * dmv[kt]);
        }

        #pragma unroll
        for (int ks = 0; ks < 2; ks++) {
            bf16x8 as = *(const bf16x8*)&Ss[16 * w + ln][ks * 32 + quad * 8];
            #pragma unroll
            for (int vt = 0; vt < 8; vt++) {
                bf16x8 bv = *(const bf16x8*)&Vs[vt * 16 + ln][ks * 32 + quad * 8];
                y[vt] = __builtin_amdgcn_mfma_f32_16x16x32_bf16(as, bv, y[vt], 0, 0, 0);
            }
        }
        __syncthreads();
    }

    #pragma unroll
    for (int vt = 0; vt < 8; vt++)
        #pragma unroll
        for (int r = 0; r < 4; r++)
            Y[(size_t)(b * LL + n0 + 16 * w + quad * 4 + r) * 1024 + h * 128 + vt * 16 + ln]
                = y[vt][r];
}

// ---------------------------------------------------------------------------
// GroupNorm + affine + gate: Z = (gn(Y)*w+b) * silu_G      (silu pre-applied)
// ---------------------------------------------------------------------------
__global__ __launch_bounds__(256) void gn_gate_kernel(
    const float* __restrict__ Y, const ushort* __restrict__ G,
    const float* __restrict__ gnw, const float* __restrict__ gnb,
    ushort* __restrict__ Z)
{
    const int t = threadIdx.x;
    const int g = blockIdx.x * 4 + (t >> 6);
    const int lane = t & 63;
    const size_t r = (size_t)(g >> 3);
    const int h = g & 7;
    const int e = h * 128 + lane * 2;
    const size_t base = r * 1024 + e;
    float2 y = *(const float2*)&Y[base];
    float s = y.x + y.y;
    float sq = y.x * y.x + y.y * y.y;
    #pragma unroll
    for (int off = 32; off >= 1; off >>= 1) {
        s  += __shfl_xor(s, off, 64);
        sq += __shfl_xor(sq, off, 64);
    }
    float mean = s * 0.0078125f;
    float var = sq * 0.0078125f - mean * mean;
    float rstd = rsqrtf(var + 1e-5f);
    float2 gw = *(const float2*)&gnw[e];
    float2 gb = *(const float2*)&gnb[e];
    uint gpk = *(const uint*)&G[base];
    float g0 = bf2f((ushort)(gpk & 0xffff));
    float g1 = bf2f((ushort)(gpk >> 16));
    uint o0 = f2bf(((y.x - mean) * rstd * gw.x + gb.x) * g0);
    uint o1 = f2bf(((y.y - mean) * rstd * gw.y + gb.y) * g1);
    *(uint*)&Z[base] = o0 | (o1 << 16);
}

// ---------------------------------------------------------------------------
extern "C" void kernel_launch(void* const* d_in, const int* in_sizes, int n_in,
                              void* d_out, int out_size, void* d_ws, size_t ws_size,
                              hipStream_t stream) {
    const float* X   = (const float*)d_in[0];
    const float* Wq  = (const float*)d_in[1];
    const float* Wk  = (const float*)d_in[2];
    const float* Wv  = (const float*)d_in[3];
    const float* Wg  = (const float*)d_in[4];
    const float* Wo  = (const float*)d_in[5];
    const float* gnw = (const float*)d_in[6];
    const float* gnb = (const float*)d_in[7];
    float* out = (float*)d_out;

    const size_t MB = 1u << 20;
    char* base = (char*)d_ws;
    float4* tbl = (float4*)base;                        // 2 MB
    ushort* Xb  = (ushort*)(base + 2 * MB);             // 16 MB
    ushort* Wqt = (ushort*)(base + 18 * MB);            // 2 MB
    ushort* Wkt = (ushort*)(base + 20 * MB);
    ushort* Wvt = (ushort*)(base + 22 * MB);
    ushort* Wgt = (ushort*)(base + 24 * MB);
    ushort* Wot = (ushort*)(base + 26 * MB);
    ushort* Qb  = (ushort*)(base + 28 * MB);            // 16 MB (later Z)
    ushort* Kb  = (ushort*)(base + 44 * MB);            // 16 MB
    ushort* Vb  = (ushort*)(base + 60 * MB);            // 16 MB (later G)
    ushort* Vt  = (ushort*)(base + 76 * MB);            // 16 MB
    float*  Yp  = (float*) (base + 92 * MB);            // 32 MB -> 124 MB total
    ushort* Gb  = Vb;
    ushort* Zb  = Qb;

    Gammas gp;
    for (int h = 0; h < 8; h++) {
        double lin = log(1.0 / 32.0) +
                     (log(1.0 / 512.0) - log(1.0 / 32.0)) * (double)h / 7.0;
        float gamma = 1.0f - expf((float)lin);
        gp.lg2[h] = log2f(gamma);
    }

    xpos_table_kernel<<<(LL * 64) / 256, 256, 0, stream>>>(tbl);
    cast_kernel<<<MM * 1024 / 1024, 256, 0, stream>>>(X, Xb);

    dim3 wgrid(16, 16);
    wtrans_kernel<<<wgrid, 256, 0, stream>>>(Wq, Wqt, 1);
    wtrans_kernel<<<wgrid, 256, 0, stream>>>(Wk, Wkt, 1);
    wtrans_kernel<<<wgrid, 256, 0, stream>>>(Wv, Wvt, 1);
    wtrans_kernel<<<wgrid, 256, 0, stream>>>(Wg, Wgt, 0);
    wtrans_kernel<<<wgrid, 256, 0, stream>>>(Wo, Wot, 0);

    dim3 ggrid(8, 64);
    mm_kernel<<<ggrid, 256, 0, stream>>>(Xb, Wqt, Qb, 1, tbl);
    mm_kernel<<<ggrid, 256, 0, stream>>>(Xb, Wkt, Kb, 2, tbl);
    mm_kernel<<<ggrid, 256, 0, stream>>>(Xb, Wvt, Vb, 0, tbl);

    vtrans_kernel<<<dim3(16, 128), 256, 0, stream>>>(Vb, Vt);

    mm_kernel<<<ggrid, 256, 0, stream>>>(Xb, Wgt, Gb, 3, tbl);

    ret_kernel<<<dim3(32, 32), 256, 0, stream>>>(Qb, Kb, Vt, Yp, gp);

    gn_gate_kernel<<<(MM * HH) / 4, 256, 0, stream>>>(Yp, Gb, gnw, gnb, Zb);

    mm_kernel<<<ggrid, 256, 0, stream>>>(Zb, Wot, out, 4, tbl);
}

// Round 3
// 549.333 us; speedup vs baseline: 7.2630x; 1.0982x over previous
//
#include <hip/hip_runtime.h>
#include <cmath>

#define BB 4
#define LL 2048
#define DD 1024
#define HH 8
#define MM (BB * LL)   // 8192 rows

struct Gammas { float lg2[8]; };
struct MMArgs { const ushort* Bt[4]; void* C[4]; int emode[4]; };

typedef __attribute__((ext_vector_type(8))) short bf16x8;
typedef __attribute__((ext_vector_type(4))) float f32x4;

__device__ __forceinline__ ushort f2bf(float f) {
    uint u = __builtin_bit_cast(uint, f);
    uint r = (u + 0x7fffu + ((u >> 16) & 1u)) >> 16;
    return (ushort)r;
}
__device__ __forceinline__ float bf2f(ushort h) {
    uint u = ((uint)h) << 16;
    return __builtin_bit_cast(float, u);
}
__device__ __forceinline__ void gload16(const void* g, void* l) {
    __builtin_amdgcn_global_load_lds((const __attribute__((address_space(1))) void*)g,
                                     (__attribute__((address_space(3))) void*)l, 16, 0, 0);
}

// ---------------------------------------------------------------------------
// xpos table: tbl[l*64 + i] = {cos*scale, sin*scale, cos/scale, sin/scale}
// ---------------------------------------------------------------------------
__global__ void xpos_table_kernel(float4* __restrict__ tbl) {
    int tid = blockIdx.x * blockDim.x + threadIdx.x;
    if (tid >= LL * 64) return;
    int l = tid >> 6, i = tid & 63;
    float inv = powf(10000.0f, -(float)i / 64.0f);
    float ang = (float)l * inv;
    float s = sinf(ang), c = cosf(ang);
    float base = (2.0f * (float)i + 51.2f) / 179.2f;
    float sc = powf(base, (float)l / 512.0f);
    tbl[tid] = make_float4(c * sc, s * sc, c / sc, s / sc);
}

__global__ __launch_bounds__(256) void cast_kernel(const float* __restrict__ X,
                                                   ushort* __restrict__ Xb) {
    int i = (blockIdx.x * 256 + threadIdx.x) * 4;
    float4 v = *(const float4*)&X[i];
    ushort4 o;
    o.x = f2bf(v.x); o.y = f2bf(v.y); o.z = f2bf(v.z); o.w = f2bf(v.w);
    *(ushort4*)&Xb[i] = o;
}

// ---------------------------------------------------------------------------
// Weight transpose+cast: W[k][n] (flat or per-head (h,d,e)) -> Wt[n][k] bf16
// ---------------------------------------------------------------------------
__global__ __launch_bounds__(256) void wtrans_kernel(const float* __restrict__ W,
                                                     ushort* __restrict__ Wt, int perhead) {
    __shared__ float T[64][68];
    const int k0 = blockIdx.y * 64, n0 = blockIdx.x * 64;
    const int t = threadIdx.x;
    for (int f = t; f < 64 * 16; f += 256) {
        int kk = f >> 4, s = f & 15;
        int n = n0 + s * 4;
        size_t src = perhead ? (size_t)(n >> 7) * 131072 + (size_t)(k0 + kk) * 128 + (n & 127)
                             : (size_t)(k0 + kk) * 1024 + n;
        *(float4*)&T[kk][s * 4] = *(const float4*)&W[src];
    }
    __syncthreads();
    for (int f = t; f < 64 * 8; f += 256) {
        int n = f >> 3, s = f & 7;
        __align__(16) ushort tmp[8];
        #pragma unroll
        for (int j = 0; j < 8; j++) tmp[j] = f2bf(T[s * 8 + j][n]);
        *(uint4*)&Wt[(size_t)(n0 + n) * 1024 + k0 + s * 8] = *(uint4*)tmp;
    }
}

// ---------------------------------------------------------------------------
// bf16 MFMA GEMM: C = A[8192x1024] * Bt^T, multi-output (4 weight/out sets).
// emode: 1 xpos up->bf16, 2 xpos down->bf16, 3 silu->bf16, 4 plain->fp32,
//        5 V-transposed store (Vt[b][v][l] bf16)
// ---------------------------------------------------------------------------
__global__ __launch_bounds__(256) void mm_kernel(
    const ushort* __restrict__ A, MMArgs args, const float4* __restrict__ tbl)
{
    __shared__ __align__(16) ushort As[128 * 32];
    __shared__ __align__(16) ushort Bs[128 * 32];
    const int t = threadIdx.x;
    const int w = t >> 6, lane = t & 63;
    const int ln = lane & 15, quad = lane >> 4;
    const int which = blockIdx.x >> 3;
    const ushort* Bt = args.Bt[which];
    void* Cv = args.C[which];
    const int emode = args.emode[which];
    const int n0 = (blockIdx.x & 7) * 128, m0 = blockIdx.y * 128;
    const int wm = w & 1, wn = w >> 1;

    f32x4 acc[4][4];
    const f32x4 fzero = {0.f, 0.f, 0.f, 0.f};
    #pragma unroll
    for (int i = 0; i < 4; i++)
        #pragma unroll
        for (int j = 0; j < 4; j++) acc[i][j] = fzero;

    const int srow = w * 32 + (lane >> 2);
    const int scol = (lane & 3) * 8;
    const ushort* ga  = A  + (size_t)(m0 + srow) * 1024 + scol;
    const ushort* ga2 = ga + 16 * 1024;
    const ushort* gb  = Bt + (size_t)(n0 + srow) * 1024 + scol;
    const ushort* gb2 = gb + 16 * 1024;
    ushort* la  = &As[(w * 32) * 32];
    ushort* la2 = &As[(w * 32 + 16) * 32];
    ushort* lb  = &Bs[(w * 32) * 32];
    ushort* lb2 = &Bs[(w * 32 + 16) * 32];

    for (int kt = 0; kt < 1024; kt += 32) {
        gload16(ga + kt, la);
        gload16(ga2 + kt, la2);
        gload16(gb + kt, lb);
        gload16(gb2 + kt, lb2);
        __syncthreads();
        bf16x8 am[4], bn[4];
        #pragma unroll
        for (int i = 0; i < 4; i++)
            am[i] = *(const bf16x8*)&As[(wm * 64 + i * 16 + ln) * 32 + quad * 8];
        #pragma unroll
        for (int i = 0; i < 4; i++)
            bn[i] = *(const bf16x8*)&Bs[(wn * 64 + i * 16 + ln) * 32 + quad * 8];
        #pragma unroll
        for (int mi = 0; mi < 4; mi++)
            #pragma unroll
            for (int ni = 0; ni < 4; ni++)
                acc[mi][ni] = __builtin_amdgcn_mfma_f32_16x16x32_bf16(
                    am[mi], bn[ni], acc[mi][ni], 0, 0, 0);
        __syncthreads();
    }

    #pragma unroll
    for (int mi = 0; mi < 4; mi++) {
        #pragma unroll
        for (int ni = 0; ni < 4; ni++) {
            const int row0 = m0 + wm * 64 + mi * 16 + quad * 4;
            const int e = wn * 64 + ni * 16 + ln;       // col within head
            const int col = n0 + e;
            if (emode == 5) {
                const int b = row0 >> 11, l0 = row0 & (LL - 1);
                ushort4 pk;
                pk.x = f2bf(acc[mi][ni][0]); pk.y = f2bf(acc[mi][ni][1]);
                pk.z = f2bf(acc[mi][ni][2]); pk.w = f2bf(acc[mi][ni][3]);
                *(ushort4*)&((ushort*)Cv)[((size_t)(b * 1024 + col)) * 2048 + l0] = pk;
                continue;
            }
            #pragma unroll
            for (int r = 0; r < 4; r++) {
                float v = acc[mi][ni][r];
                if (emode == 1 || emode == 2) {
                    float4 tt = tbl[(size_t)((row0 + r) & (LL - 1)) * 64 + (e >> 1)];
                    float cc = (emode == 1) ? tt.x : tt.z;
                    float ss = (emode == 1) ? tt.y : tt.w;
                    float partner = __shfl_xor(v, 1);
                    float rot = (e & 1) ? partner : -partner;
                    v = v * cc + rot * ss;
                } else if (emode == 3) {
                    v = v / (1.0f + expf(-v));
                }
                if (emode == 4)
                    ((float*)Cv)[(size_t)(row0 + r) * 1024 + col] = v;
                else
                    ((ushort*)Cv)[(size_t)(row0 + r) * 1024 + col] = f2bf(v);
            }
        }
    }
}

// ---------------------------------------------------------------------------
// Retention (MFMA, balanced): block z handles query blocks z and 31-z.
// Q frags in registers; K/V register-prefetched; S via transposed-operand
// MFMA -> b64 LDS writes; per-head decay cutoff.
// ---------------------------------------------------------------------------
__global__ __launch_bounds__(256) void ret_kernel(
    const ushort* __restrict__ Qb, const ushort* __restrict__ Kb,
    const ushort* __restrict__ Vt, float* __restrict__ Y, Gammas gp)
{
    __shared__ __align__(16) ushort Ks[64 * 136];
    __shared__ __align__(16) ushort Vs[128 * 72];
    __shared__ __align__(16) ushort Ss[64 * 72];

    const int t = threadIdx.x;
    const int w = t >> 6, lane = t & 63, ln = lane & 15, quad = lane >> 4;
    const int bh = blockIdx.y, b = bh >> 3, h = bh & 7;
    const float lg2 = gp.lg2[h];
    const size_t qkbase = (size_t)b * LL * 1024 + (size_t)h * 128;
    const size_t vtbase = ((size_t)b * 1024 + h * 128) * 2048;

    // decay cutoff: skip chunks where max decay < 2^-34
    const int cap = (int)((34.0f / (-lg2) + 63.0f) * 0.015625f);

    float dmk[4], drr[4];
    #pragma unroll
    for (int kt = 0; kt < 4; kt++)
        dmk[kt] = exp2f(-(float)(kt * 16 + quad * 4) * lg2);
    #pragma unroll
    for (int r = 0; r < 4; r++)
        drr[r] = exp2f(-(float)r * lg2);

    // staging indices
    const int krow = t >> 4, kc = (t & 15) * 8;      // K: 4 x (16-row step)
    const int vrow = t >> 3, vc = (t & 7) * 8;       // V: 4 x (32-row step)

    for (int seg = 0; seg < 2; seg++) {
        const int qb = seg ? 31 - blockIdx.x : blockIdx.x;
        const int n0 = qb * 64;

        bf16x8 aq[4];
        #pragma unroll
        for (int ks = 0; ks < 4; ks++)
            aq[ks] = *(const bf16x8*)&Qb[qkbase + (size_t)(n0 + 16 * w + ln) * 1024
                                         + ks * 32 + quad * 8];
        f32x4 y[8];
        const f32x4 fzero = {0.f, 0.f, 0.f, 0.f};
        #pragma unroll
        for (int vt = 0; vt < 8; vt++) y[vt] = fzero;

        int cmin = qb - cap; if (cmin < 0) cmin = 0;

        uint4 kreg[4], vreg[4];
        {
            const int m0 = cmin * 64;
            #pragma unroll
            for (int i = 0; i < 4; i++)
                kreg[i] = *(const uint4*)&Kb[qkbase + (size_t)(m0 + krow + i * 16) * 1024 + kc];
            #pragma unroll
            for (int i = 0; i < 4; i++)
                vreg[i] = *(const uint4*)&Vt[vtbase + (size_t)(vrow + i * 32) * 2048 + m0 + vc];
        }

        for (int c = cmin; c <= qb; c++) {
            const int m0 = c * 64;
            __syncthreads();
            #pragma unroll
            for (int i = 0; i < 4; i++)
                *(uint4*)&Ks[(krow + i * 16) * 136 + kc] = kreg[i];
            #pragma unroll
            for (int i = 0; i < 4; i++)
                *(uint4*)&Vs[(vrow + i * 32) * 72 + vc] = vreg[i];
            __syncthreads();
            if (c < qb) {
                const int m1 = m0 + 64;
                #pragma unroll
                for (int i = 0; i < 4; i++)
                    kreg[i] = *(const uint4*)&Kb[qkbase + (size_t)(m1 + krow + i * 16) * 1024 + kc];
                #pragma unroll
                for (int i = 0; i < 4; i++)
                    vreg[i] = *(const uint4*)&Vt[vtbase + (size_t)(vrow + i * 32) * 2048 + m1 + vc];
            }

            // S^T blocks: mfma(bk, aq) -> lane holds S[n=16w+ln][m=kt*16+quad*4+r]
            f32x4 s4[4];
            #pragma unroll
            for (int kt = 0; kt < 4; kt++) s4[kt] = fzero;
            #pragma unroll
            for (int ks = 0; ks < 4; ks++) {
                #pragma unroll
                for (int kt = 0; kt < 4; kt++) {
                    bf16x8 bk = *(const bf16x8*)&Ks[(kt * 16 + ln) * 136 + ks * 32 + quad * 8];
                    s4[kt] = __builtin_amdgcn_mfma_f32_16x16x32_bf16(bk, aq[ks], s4[kt], 0, 0, 0);
                }
            }

            const float dq = exp2f((float)(n0 - m0 + 16 * w + ln) * lg2);
            if (c == qb) {
                #pragma unroll
                for (int kt = 0; kt < 4; kt++) {
                    const float db = dq * dmk[kt];
                    ushort4 pk;
                    pk.x = f2bf((kt * 16 + quad * 4 + 0 <= 16 * w + ln) ? s4[kt][0] * db * drr[0] : 0.f);
                    pk.y = f2bf((kt * 16 + quad * 4 + 1 <= 16 * w + ln) ? s4[kt][1] * db * drr[1] : 0.f);
                    pk.z = f2bf((kt * 16 + quad * 4 + 2 <= 16 * w + ln) ? s4[kt][2] * db * drr[2] : 0.f);
                    pk.w = f2bf((kt * 16 + quad * 4 + 3 <= 16 * w + ln) ? s4[kt][3] * db * drr[3] : 0.f);
                    *(ushort4*)&Ss[(16 * w + ln) * 72 + kt * 16 + quad * 4] = pk;
                }
            } else {
                #pragma unroll
                for (int kt = 0; kt < 4; kt++) {
                    const float db = dq * dmk[kt];
                    ushort4 pk;
                    pk.x = f2bf(s4[kt][0] * db * drr[0]);
                    pk.y = f2bf(s4[kt][1] * db * drr[1]);
                    pk.z = f2bf(s4[kt][2] * db * drr[2]);
                    pk.w = f2bf(s4[kt][3] * db * drr[3]);
                    *(ushort4*)&Ss[(16 * w + ln) * 72 + kt * 16 + quad * 4] = pk;
                }
            }

            // Y += S * V   (Ss rows are wave-private: no barrier needed)
            #pragma unroll
            for (int ks2 = 0; ks2 < 2; ks2++) {
                bf16x8 as = *(const bf16x8*)&Ss[(16 * w + ln) * 72 + ks2 * 32 + quad * 8];
                #pragma unroll
                for (int vt = 0; vt < 8; vt++) {
                    bf16x8 bv = *(const bf16x8*)&Vs[(vt * 16 + ln) * 72 + ks2 * 32 + quad * 8];
                    y[vt] = __builtin_amdgcn_mfma_f32_16x16x32_bf16(as, bv, y[vt], 0, 0, 0);
                }
            }
        }

        #pragma unroll
        for (int vt = 0; vt < 8; vt++)
            #pragma unroll
            for (int r = 0; r < 4; r++)
                Y[(size_t)(b * LL + n0 + 16 * w + quad * 4 + r) * 1024
                  + h * 128 + vt * 16 + ln] = y[vt][r];
    }
}

// ---------------------------------------------------------------------------
// GroupNorm + affine + gate
// ---------------------------------------------------------------------------
__global__ __launch_bounds__(256) void gn_gate_kernel(
    const float* __restrict__ Y, const ushort* __restrict__ G,
    const float* __restrict__ gnw, const float* __restrict__ gnb,
    ushort* __restrict__ Z)
{
    const int t = threadIdx.x;
    const int g = blockIdx.x * 4 + (t >> 6);
    const int lane = t & 63;
    const size_t r = (size_t)(g >> 3);
    const int h = g & 7;
    const int e = h * 128 + lane * 2;
    const size_t base = r * 1024 + e;
    float2 y = *(const float2*)&Y[base];
    float s = y.x + y.y;
    float sq = y.x * y.x + y.y * y.y;
    #pragma unroll
    for (int off = 32; off >= 1; off >>= 1) {
        s  += __shfl_xor(s, off, 64);
        sq += __shfl_xor(sq, off, 64);
    }
    float mean = s * 0.0078125f;
    float var = sq * 0.0078125f - mean * mean;
    float rstd = rsqrtf(var + 1e-5f);
    float2 gw = *(const float2*)&gnw[e];
    float2 gb = *(const float2*)&gnb[e];
    uint gpk = *(const uint*)&G[base];
    float g0 = bf2f((ushort)(gpk & 0xffff));
    float g1 = bf2f((ushort)(gpk >> 16));
    uint o0 = f2bf(((y.x - mean) * rstd * gw.x + gb.x) * g0);
    uint o1 = f2bf(((y.y - mean) * rstd * gw.y + gb.y) * g1);
    *(uint*)&Z[base] = o0 | (o1 << 16);
}

// ---------------------------------------------------------------------------
extern "C" void kernel_launch(void* const* d_in, const int* in_sizes, int n_in,
                              void* d_out, int out_size, void* d_ws, size_t ws_size,
                              hipStream_t stream) {
    const float* X   = (const float*)d_in[0];
    const float* Wq  = (const float*)d_in[1];
    const float* Wk  = (const float*)d_in[2];
    const float* Wv  = (const float*)d_in[3];
    const float* Wg  = (const float*)d_in[4];
    const float* Wo  = (const float*)d_in[5];
    const float* gnw = (const float*)d_in[6];
    const float* gnb = (const float*)d_in[7];
    float* out = (float*)d_out;

    const size_t MB = 1u << 20;
    char* base = (char*)d_ws;
    float4* tbl = (float4*)base;                        // 2 MB
    ushort* Xb  = (ushort*)(base + 2 * MB);             // 16 MB
    ushort* Wqt = (ushort*)(base + 18 * MB);
    ushort* Wkt = (ushort*)(base + 20 * MB);
    ushort* Wvt = (ushort*)(base + 22 * MB);
    ushort* Wgt = (ushort*)(base + 24 * MB);
    ushort* Wot = (ushort*)(base + 26 * MB);
    ushort* Qb  = (ushort*)(base + 28 * MB);            // 16 MB (later Z)
    ushort* Kb  = (ushort*)(base + 44 * MB);            // 16 MB
    ushort* Gb  = (ushort*)(base + 60 * MB);            // 16 MB
    ushort* Vt  = (ushort*)(base + 76 * MB);            // 16 MB
    float*  Yp  = (float*) (base + 92 * MB);            // 32 MB -> 124 MB
    ushort* Zb  = Qb;

    Gammas gp;
    for (int h = 0; h < 8; h++) {
        double lin = log(1.0 / 32.0) +
                     (log(1.0 / 512.0) - log(1.0 / 32.0)) * (double)h / 7.0;
        float gamma = 1.0f - expf((float)lin);
        gp.lg2[h] = log2f(gamma);
    }

    xpos_table_kernel<<<(LL * 64) / 256, 256, 0, stream>>>(tbl);
    cast_kernel<<<MM * 1024 / 1024, 256, 0, stream>>>(X, Xb);

    dim3 wgrid(16, 16);
    wtrans_kernel<<<wgrid, 256, 0, stream>>>(Wq, Wqt, 1);
    wtrans_kernel<<<wgrid, 256, 0, stream>>>(Wk, Wkt, 1);
    wtrans_kernel<<<wgrid, 256, 0, stream>>>(Wv, Wvt, 1);
    wtrans_kernel<<<wgrid, 256, 0, stream>>>(Wg, Wgt, 0);
    wtrans_kernel<<<wgrid, 256, 0, stream>>>(Wo, Wot, 0);

    // fused Q/K/V/G projections (V written directly transposed into Vt)
    MMArgs qa;
    qa.Bt[0] = Wqt; qa.Bt[1] = Wkt; qa.Bt[2] = Wvt; qa.Bt[3] = Wgt;
    qa.C[0] = Qb;   qa.C[1] = Kb;   qa.C[2] = Vt;   qa.C[3] = Gb;
    qa.emode[0] = 1; qa.emode[1] = 2; qa.emode[2] = 5; qa.emode[3] = 3;
    mm_kernel<<<dim3(32, 64), 256, 0, stream>>>(Xb, qa, tbl);

    ret_kernel<<<dim3(16, 32), 256, 0, stream>>>(Qb, Kb, Vt, Yp, gp);

    gn_gate_kernel<<<(MM * HH) / 4, 256, 0, stream>>>(Yp, Gb, gnw, gnb, Zb);

    MMArgs oa;
    oa.Bt[0] = Wot; oa.Bt[1] = Wot; oa.Bt[2] = Wot; oa.Bt[3] = Wot;
    oa.C[0] = out;  oa.C[1] = out;  oa.C[2] = out;  oa.C[3] = out;
    oa.emode[0] = 4; oa.emode[1] = 4; oa.emode[2] = 4; oa.emode[3] = 4;
    mm_kernel<<<dim3(8, 64), 256, 0, stream>>>(Zb, oa, tbl);
}